// Round 1
// baseline (315.840 us; speedup 1.0000x reference)
//
#include <hip/hip_runtime.h>

// Direct 3x3 VALID conv, fp32, x:(16,2048,2048), k:(16,16,3,3) -> out:(16,2046,2046)
// Each thread: 16 c_out x 4 w outputs at one h. Weights staged in LDS as
// [ci][kh][kw][co] for contiguous float4 broadcast reads.

#define CIN   16
#define COUT  16
#define HIN   2048
#define WIN   2048
#define HOUT  2046
#define WOUT  2046
#define RW    4     // outputs per thread along W
#define WT    64    // w-thread-groups per block
#define HT    4     // h rows per block

__global__ __launch_bounds__(256, 4)
void conv3x3_direct(const float* __restrict__ x,
                    const float* __restrict__ k,
                    float* __restrict__ out) {
    __shared__ float lw[CIN * 3 * 3 * COUT];   // [ci][kh][kw][co], 9216 B

    const int tid = threadIdx.x;
    // Cooperative transpose-load of weights into LDS.
    for (int idx = tid; idx < CIN * 9 * COUT; idx += 256) {
        int co = idx & 15;
        int r  = idx >> 4;          // ci*9 + kh*3 + kw
        int kw = r % 3;
        int r2 = r / 3;
        int kh = r2 % 3;
        int ci = r2 / 3;
        lw[idx] = k[co * (CIN * 9) + ci * 9 + kh * 3 + kw];
    }
    __syncthreads();

    const int wt = tid & (WT - 1);
    const int ht = tid >> 6;                      // 0..3
    int w0 = (blockIdx.x * WT + wt) * RW;         // 0..2044 step 4
    if (w0 > WOUT - RW) w0 = WOUT - RW;           // clamp -> 2042 (duplicate, identical)
    int h = blockIdx.y * HT + ht;
    if (h > HOUT - 1) h = HOUT - 1;               // clamp (duplicate, identical)

    float acc[COUT][RW];
    #pragma unroll
    for (int c = 0; c < COUT; ++c)
        #pragma unroll
        for (int r = 0; r < RW; ++r) acc[c][r] = 0.0f;

    const float* xp = x + h * WIN + w0;

    for (int ci = 0; ci < CIN; ++ci) {
        #pragma unroll
        for (int kh = 0; kh < 3; ++kh) {
            const float* rowp = xp + ci * (HIN * WIN) + kh * WIN;
            // 6 input cols, always 8B-aligned (w0 even, WIN even)
            float2 a = *(const float2*)(rowp);
            float2 b = *(const float2*)(rowp + 2);
            float2 c = *(const float2*)(rowp + 4);
            float in6[6];
            in6[0] = a.x; in6[1] = a.y;
            in6[2] = b.x; in6[3] = b.y;
            in6[4] = c.x; in6[5] = c.y;

            const float* lwp = &lw[(ci * 3 + kh) * 48];  // [kw][co]
            #pragma unroll
            for (int kw = 0; kw < 3; ++kw) {
                #pragma unroll
                for (int cg = 0; cg < 4; ++cg) {
                    float4 w4 = *(const float4*)&lwp[kw * 16 + cg * 4];
                    const float wv[4] = {w4.x, w4.y, w4.z, w4.w};
                    #pragma unroll
                    for (int j = 0; j < 4; ++j) {
                        #pragma unroll
                        for (int r = 0; r < RW; ++r)
                            acc[cg * 4 + j][r] += in6[r + kw] * wv[j];
                    }
                }
            }
        }
    }

    // Store: 16 co x 4 w as 2x float2 (8B-aligned: w0 even, WOUT even)
    float* op = out + h * WOUT + w0;
    #pragma unroll
    for (int co = 0; co < COUT; ++co) {
        float* p = op + co * (HOUT * WOUT);
        *(float2*)(p)     = make_float2(acc[co][0], acc[co][1]);
        *(float2*)(p + 2) = make_float2(acc[co][2], acc[co][3]);
    }
}

extern "C" void kernel_launch(void* const* d_in, const int* in_sizes, int n_in,
                              void* d_out, int out_size, void* d_ws, size_t ws_size,
                              hipStream_t stream) {
    const float* x = (const float*)d_in[0];
    const float* k = (const float*)d_in[1];
    float* out = (float*)d_out;
    // w: 512 thread-groups of RW=4 -> 8 blocks of 64; h: ceil(2046/4)=512
    dim3 grid(8, 512);
    conv3x3_direct<<<grid, 256, 0, stream>>>(x, k, out);
}

// Round 2
// 200.863 us; speedup vs baseline: 1.5724x; 1.5724x over previous
//
#include <hip/hip_runtime.h>

// 3x3 VALID conv via bf16 MFMA implicit GEMM.
// x:(16,2048,2048) fp32, k:(16,16,3,3) fp32 -> out:(16,2046,2046) fp32
// Per 16x16 mfma: A = weights (M=co=16, K), B = im2col (K, N=16 spatial w),
// K = tap*16+ci, padded 144->160 (5 mfma, dead K has zero weights).

#define HIN   2048
#define WIN   2048
#define HOUT  2046
#define WOUT  2046
#define PLANE_IN  (HIN * WIN)
#define PLANE_OUT (HOUT * WOUT)
#define BH 32
#define BW 32
#define TR 34
#define TC 34
#define NPOS (TR * TC)

typedef __attribute__((ext_vector_type(8))) short bf16x8;
typedef __attribute__((ext_vector_type(4))) float f32x4;

static __device__ __forceinline__ short f2bf(float f) {
    unsigned u = __float_as_uint(f);
    unsigned r = (u + 0x7FFFu + ((u >> 16) & 1u)) >> 16;   // RNE
    return (short)r;
}

__global__ __launch_bounds__(256, 4)
void conv3x3_mfma(const float* __restrict__ x,
                  const float* __restrict__ k,
                  float* __restrict__ out) {
    __shared__ short lds[NPOS * 16];   // [pos][ci] bf16, 36992 B

    const int tid  = threadIdx.x;
    const int lane = tid & 63;
    const int wv   = tid >> 6;
    const int m    = lane & 15;   // A: co row; B: spatial col; D: col
    const int g    = lane >> 4;   // k-group

    // XCD-chunked bijective swizzle: 4096 blocks = 8 XCDs x 512
    int bid = blockIdx.x;
    int swz = (bid & 7) * 512 + (bid >> 3);
    int h0 = (swz >> 6) * BH;
    int w0 = (swz & 63) * BW;

    // ---- stage input tile: fp32 -> bf16, [pos][ci], 16B-slot XOR swizzle ----
    for (int p = tid; p < NPOS; p += 256) {
        int r = p / TC;
        int c = p - r * TC;
        int hh = h0 + r; if (hh > HIN - 1) hh = HIN - 1;
        int ww = w0 + c; if (ww > WIN - 1) ww = WIN - 1;
        const float* gp = x + hh * WIN + ww;
        short t[16];
        #pragma unroll
        for (int ci = 0; ci < 16; ++ci) t[ci] = f2bf(gp[ci * PLANE_IN]);
        bf16x8 lo, hi;
        #pragma unroll
        for (int j = 0; j < 8; ++j) { lo[j] = t[j]; hi[j] = t[8 + j]; }
        int sw = (c >> 2) & 1;                 // swizzle: which 16B slot gets lo
        bf16x8* dst = (bf16x8*)&lds[p * 16];
        dst[sw]     = lo;
        dst[1 - sw] = hi;
    }

    // ---- weight A-fragments: lane holds A[row=co=m][k=g*8+j], k>=144 -> 0 ----
    bf16x8 wf[5];
    #pragma unroll
    for (int i = 0; i < 5; ++i) {
        #pragma unroll
        for (int j = 0; j < 8; ++j) {
            int kg  = 32 * i + 8 * g + j;
            int tap = kg >> 4;          // kh*3+kw
            int ci  = kg & 15;
            short v = 0;
            if (tap < 9) v = f2bf(k[(m * 16 + ci) * 9 + tap]);
            wf[i][j] = v;
        }
    }

    // ---- per-lane B-fragment LDS byte offsets (tile-base added later) ----
    int off[5];
    #pragma unroll
    for (int i = 0; i < 5; ++i) {
        int tap = 2 * i + (g >> 1);
        if (tap > 8) tap = 8;           // dead K: any valid addr, weights are 0
        int kh = tap / 3;
        int kw = tap - kh * 3;
        int ci0 = (g & 1) * 8;
        int col = m + kw;               // wl (0/16) added via tile base
        int o = (kh * TC + col) * 32 + ci0 * 2;
        off[i] = o ^ ((col & 4) << 2);  // matches staging-side swizzle
    }

    __syncthreads();

    const char* ldsb = (const char*)lds;
    const int coBase = g * 4;

    for (int hl8 = 0; hl8 < 8; ++hl8) {
        int hl = wv * 8 + hl8;          // each wave owns 8 output rows
        int h  = h0 + hl;
        bool hok = (h < HOUT);          // wave-uniform
        #pragma unroll
        for (int half = 0; half < 2; ++half) {
            int wl = half * 16;
            int tb = (hl * TC + wl) * 32;
            f32x4 acc = {0.f, 0.f, 0.f, 0.f};
            #pragma unroll
            for (int i = 0; i < 5; ++i) {
                bf16x8 b = *(const bf16x8*)(ldsb + (tb + off[i]));
                acc = __builtin_amdgcn_mfma_f32_16x16x32_bf16(wf[i], b, acc, 0, 0, 0);
            }
            int w = w0 + wl + m;
            if (hok && w < WOUT) {
                float* op = out + h * WOUT + w;
                #pragma unroll
                for (int r = 0; r < 4; ++r)       // D: row=co=(g*4+r), col=m
                    op[(coBase + r) * PLANE_OUT] = acc[r];
            }
        }
    }
}

extern "C" void kernel_launch(void* const* d_in, const int* in_sizes, int n_in,
                              void* d_out, int out_size, void* d_ws, size_t ws_size,
                              hipStream_t stream) {
    const float* x = (const float*)d_in[0];
    const float* k = (const float*)d_in[1];
    float* out = (float*)d_out;
    conv3x3_mfma<<<dim3(4096), dim3(256), 0, stream>>>(x, k, out);
}